// Round 2
// baseline (8289.823 us; speedup 1.0000x reference)
//
#include <hip/hip_runtime.h>
#include <hip/hip_bf16.h>

#define B_ 4
#define C_ 80
#define T_ 800
#define R_ 3200   // B_*T_
#define DIN 160
#define NST 16

typedef const float* fp;

__device__ __forceinline__ float blockSum(float v, float* sb) {
  for (int o = 32; o; o >>= 1) v += __shfl_xor(v, o);
  __syncthreads();
  if ((threadIdx.x & 63) == 0) sb[threadIdx.x >> 6] = v;
  __syncthreads();
  return sb[0] + sb[1] + sb[2] + sb[3];
}
__device__ __forceinline__ float blockMax(float v, float* sb) {
  for (int o = 32; o; o >>= 1) v = fmaxf(v, __shfl_xor(v, o));
  __syncthreads();
  if ((threadIdx.x & 63) == 0) sb[threadIdx.x >> 6] = v;
  __syncthreads();
  return fmaxf(fmaxf(sb[0], sb[1]), fmaxf(sb[2], sb[3]));
}

// ---- CMN + transpose: feat [B,C,T] -> x [B*T, C] ----------------------------
__global__ __launch_bounds__(256) void cmn_k(fp feat, float* __restrict__ x) {
  int bc = blockIdx.x;           // 0..319
  int b = bc / C_, c = bc % C_;
  const float* f = feat + (b * C_ + c) * T_;
  __shared__ float sb[4];
  int tid = threadIdx.x;
  float v[4]; float s = 0.f;
  #pragma unroll
  for (int i = 0; i < 4; ++i) {
    int t = tid + i * 256;
    v[i] = (t < T_) ? f[t] : 0.f;
    s += v[i];
  }
  s = blockSum(s, sb);
  float mu = s * (1.f / T_);
  #pragma unroll
  for (int i = 0; i < 4; ++i) {
    int t = tid + i * 256;
    if (t < T_) x[(b * T_ + t) * C_ + c] = v[i] - mu;
  }
}

// ---- LayerNorm over C=80, one wave per row ----------------------------------
__global__ __launch_bounds__(256) void ln_k(const float* __restrict__ in, fp g, fp be,
                                            float* __restrict__ out) {
  int w = threadIdx.x >> 6, lane = threadIdx.x & 63;
  int row = blockIdx.x * 4 + w;
  const float* xr = in + row * C_;
  float v0 = xr[lane];
  float v1 = (lane < 16) ? xr[64 + lane] : 0.f;
  float s = v0 + v1;
  for (int o = 32; o; o >>= 1) s += __shfl_xor(s, o);
  float mu = s * (1.f / C_);
  float d0 = v0 - mu;
  float d1 = (lane < 16) ? (v1 - mu) : 0.f;
  float q = d0 * d0 + d1 * d1;
  for (int o = 32; o; o >>= 1) q += __shfl_xor(q, o);
  float rs = rsqrtf(q * (1.f / C_) + 1e-5f);
  out[row * C_ + lane] = d0 * rs * g[lane] + be[lane];
  if (lane < 16)
    out[row * C_ + 64 + lane] = d1 * rs * g[64 + lane] + be[64 + lane];
}

// ---- generic fp32 GEMM: out[M=3200,N] = (A (+A2)) @ W + epilogue ------------
// EPI: 0=plain 1=bias+gelu 2=bias+residual(extra) 3=att1(pack in extra) 4=bias
template<int EPI>
__global__ __launch_bounds__(256) void gemm_k(const float* __restrict__ A,
    const float* __restrict__ A2, fp W, fp bias,
    const float* __restrict__ extra, float* __restrict__ out, int N, int K) {
  __shared__ float As[64][81];
  __shared__ float Ws[80][64];
  int tid = threadIdx.x;
  int c0 = blockIdx.x * 64;
  int row0 = blockIdx.y * 64;
  int ty = tid >> 4, tx = tid & 15;
  float acc[4][4] = {};
  for (int k0 = 0; k0 < K; k0 += 80) {
    for (int e = tid; e < 64 * 80; e += 256) {
      int r = e / 80, k = e % 80;
      int gk = k0 + k;
      float v = 0.f;
      if (gk < K) {
        v = A[(row0 + r) * K + gk];
        if (A2) v += A2[(row0 + r) * K + gk];
      }
      As[r][k] = v;
    }
    for (int e = tid; e < 80 * 64; e += 256) {
      int k = e >> 6, c = e & 63;
      int gk = k0 + k, gc = c0 + c;
      Ws[k][c] = (gk < K && gc < N) ? W[gk * N + gc] : 0.f;
    }
    __syncthreads();
    #pragma unroll 4
    for (int k = 0; k < 80; ++k) {
      float a0 = As[ty * 4 + 0][k], a1 = As[ty * 4 + 1][k];
      float a2 = As[ty * 4 + 2][k], a3 = As[ty * 4 + 3][k];
      float w0 = Ws[k][tx * 4 + 0], w1 = Ws[k][tx * 4 + 1];
      float w2 = Ws[k][tx * 4 + 2], w3 = Ws[k][tx * 4 + 3];
      acc[0][0] += a0 * w0; acc[0][1] += a0 * w1; acc[0][2] += a0 * w2; acc[0][3] += a0 * w3;
      acc[1][0] += a1 * w0; acc[1][1] += a1 * w1; acc[1][2] += a1 * w2; acc[1][3] += a1 * w3;
      acc[2][0] += a2 * w0; acc[2][1] += a2 * w1; acc[2][2] += a2 * w2; acc[2][3] += a2 * w3;
      acc[3][0] += a3 * w0; acc[3][1] += a3 * w1; acc[3][2] += a3 * w2; acc[3][3] += a3 * w3;
    }
    __syncthreads();
  }
  #pragma unroll
  for (int i = 0; i < 4; ++i) {
    int row = row0 + ty * 4 + i;
    #pragma unroll
    for (int j = 0; j < 4; ++j) {
      int c = c0 + tx * 4 + j;
      if (c < N) {
        float v = acc[i][j];
        if (EPI == 1) { v += bias[c]; v = 0.5f * v * (1.f + erff(v * 0.70710678118f)); }
        else if (EPI == 2) { v += bias[c] + extra[row * N + c]; }
        else if (EPI == 3) {
          v += extra[(row / T_) * 128 + c];
          v = fmaxf(v, 0.f);
          v = v * extra[512 + c] + extra[640 + c];
          v = tanhf(v);
        }
        else if (EPI == 4) { v += bias[c]; }
        out[row * N + c] = v;
      }
    }
  }
}

// ---- causal depthwise conv (K=4) + SiLU, both directions --------------------
__global__ __launch_bounds__(256) void conv_k(const float* __restrict__ xz, fp cw, fp cb,
                                              float* __restrict__ xcf, float* __restrict__ xcb) {
  int idx = blockIdx.x * 256 + threadIdx.x;
  if (idx >= 2 * R_ * DIN) return;
  int dir = idx / (R_ * DIN);
  int rem = idx % (R_ * DIN);
  int r = rem / DIN, d = rem % DIN;
  int b = r / T_, t = r % T_;
  float acc = cb[d];
  #pragma unroll
  for (int k = 0; k < 4; ++k) {
    int tt = t - 3 + k;
    if (tt >= 0) {
      int src = dir ? (T_ - 1 - tt) : tt;
      acc += cw[k * DIN + d] * xz[(b * T_ + src) * 320 + d];
    }
  }
  float sg = 1.f / (1.f + expf(-acc));
  (dir ? xcb : xcf)[r * DIN + d] = acc * sg;
}

// ---- fused x_proj + dt_proj + softplus, per row -----------------------------
__global__ __launch_bounds__(128) void xdt_k(const float* __restrict__ xcf,
    const float* __restrict__ xcb, fp xp, fp dtw, fp dtb,
    float* __restrict__ dbc2, float* __restrict__ dt2, float* __restrict__ dtx2) {
  int row = blockIdx.x;               // 0..6399 = dir*R_ + r
  int dir = row / R_, r = row % R_;
  const float* xc = (dir ? xcb : xcf) + r * DIN;
  __shared__ float xl[DIN];
  __shared__ float dl_[5];
  int tid = threadIdx.x;
  for (int e = tid; e < DIN; e += 128) xl[e] = xc[e];
  __syncthreads();
  if (tid < 37) {
    float acc = 0.f;
    for (int i = 0; i < DIN; ++i) acc += xl[i] * xp[i * 37 + tid];
    dbc2[row * 37 + tid] = acc;
    if (tid < 5) dl_[tid] = acc;
  }
  __syncthreads();
  for (int j = tid; j < DIN; j += 128) {
    float v = dtb[j];
    #pragma unroll
    for (int i = 0; i < 5; ++i) v += dl_[i] * dtw[i * DIN + j];
    v = fmaxf(v, 0.f) + log1pf(expf(-fabsf(v)));    // stable softplus
    dt2[row * DIN + j] = v;
    dtx2[row * DIN + j] = v * xl[j];
  }
}

// ---- selective scan, both dirs; gating fused; bwd written un-flipped --------
__global__ __launch_bounds__(256) void scan_k(const float* __restrict__ dt2,
    const float* __restrict__ dtx2, const float* __restrict__ dbc2,
    const float* __restrict__ xcf, const float* __restrict__ xcb,
    const float* __restrict__ xz, fp A_log, fp Dp,
    float* __restrict__ ygf, float* __restrict__ ygb) {
  int bi = blockIdx.x;                 // 0..79
  int dblk = bi % 10, b = (bi / 10) % B_, dir = bi / 40;
  int d0 = dblk * 16;
  int tid = threadIdx.x;
  int dl = tid >> 4, n = tid & 15;
  int d = d0 + dl;
  float Areg = -expf(A_log[d * NST + n]);
  float Dv = Dp[d];
  const float* xc = dir ? xcb : xcf;
  float* yg = dir ? ygb : ygf;
  __shared__ float sdt[50][16], sdx[50][16], sB[50][16], sC[50][16];
  float h = 0.f;
  int rbase = dir * R_ + b * T_;
  for (int tc = 0; tc < 16; ++tc) {
    int t0 = tc * 50;
    for (int e = tid; e < 800; e += 256) {
      int i = e >> 4, j = e & 15;
      int grow = rbase + t0 + i;
      sdt[i][j] = dt2[grow * DIN + d0 + j];
      sdx[i][j] = dtx2[grow * DIN + d0 + j];
      sB[i][j] = dbc2[grow * 37 + 5 + j];
      sC[i][j] = dbc2[grow * 37 + 21 + j];
    }
    __syncthreads();
    for (int i = 0; i < 50; ++i) {
      float dA = expf(sdt[i][dl] * Areg);
      h = dA * h + sdx[i][dl] * sB[i][n];
      float y = h * sC[i][n];
      y += __shfl_xor(y, 1);
      y += __shfl_xor(y, 2);
      y += __shfl_xor(y, 4);
      y += __shfl_xor(y, 8);
      if (n == 0) {
        int t = t0 + i;
        int rloc = b * T_ + t;
        float xcv = xc[rloc * DIN + d];
        int orow = dir ? (b * T_ + (T_ - 1 - t)) : rloc;
        float z = xz[orow * 320 + 160 + d];
        float sg = 1.f / (1.f + expf(-z));
        yg[orow * DIN + d] = (y + xcv * Dv) * (z * sg);
      }
    }
    __syncthreads();
  }
}

// ---- pooling: per-(b,c) mean/std over T -------------------------------------
__global__ __launch_bounds__(256) void stats_k(const float* __restrict__ x,
                                               float* __restrict__ meanv, float* __restrict__ stdv) {
  int bc = blockIdx.x; int b = bc / C_, c = bc % C_;
  __shared__ float sb[4];
  int tid = threadIdx.x;
  float v[4]; float s = 0.f;
  #pragma unroll
  for (int i = 0; i < 4; ++i) {
    int t = tid + i * 256;
    v[i] = (t < T_) ? x[(b * T_ + t) * C_ + c] : 0.f;
    s += v[i];
  }
  s = blockSum(s, sb);
  float mu = s * (1.f / T_);
  float q = 0.f;
  #pragma unroll
  for (int i = 0; i < 4; ++i) {
    int t = tid + i * 256;
    if (t < T_) { float dd = v[i] - mu; q += dd * dd; }
  }
  q = blockSum(q, sb);
  if (tid == 0) { meanv[bc] = mu; stdv[bc] = sqrtf(fmaxf(q * (1.f / T_), 1e-12f)); }
}

// ---- att1 pack: bias2[b][d] (mean/std branches + b1), bn1 affine ------------
__global__ __launch_bounds__(256) void prep_k(const float* __restrict__ meanv,
    const float* __restrict__ stdv, fp w1, fp ab1, fp g1p, fp b1p, fp m1p, fp v1p,
    float* __restrict__ pack) {
  int idx = blockIdx.x * 256 + threadIdx.x;
  if (idx < 512) {
    int b = idx / 128, dcol = idx % 128;
    float acc = ab1[dcol];
    for (int c = 0; c < C_; ++c) {
      acc += meanv[b * C_ + c] * w1[(C_ + c) * 128 + dcol];
      acc += stdv[b * C_ + c] * w1[(2 * C_ + c) * 128 + dcol];
    }
    pack[idx] = acc;
  } else if (idx < 640) {
    int dcol = idx - 512;
    float kv = g1p[dcol] * rsqrtf(v1p[dcol] + 1e-5f);
    pack[512 + dcol] = kv;
    pack[640 + dcol] = b1p[dcol] - m1p[dcol] * kv;
  }
}

// ---- softmax over T + weighted stats + bn2 ----------------------------------
__global__ __launch_bounds__(256) void pool_k(const float* __restrict__ x,
    const float* __restrict__ scores, fp g2, fp b2, fp m2, fp v2,
    float* __restrict__ pooledn) {
  int bc = blockIdx.x; int b = bc / C_, c = bc % C_;
  __shared__ float sb[4];
  int tid = threadIdx.x;
  float sv[4], xv[4];
  float mx = -1e30f;
  #pragma unroll
  for (int i = 0; i < 4; ++i) {
    int t = tid + i * 256;
    if (t < T_) { sv[i] = scores[(b * T_ + t) * C_ + c]; xv[i] = x[(b * T_ + t) * C_ + c]; }
    else { sv[i] = -1e30f; xv[i] = 0.f; }
    mx = fmaxf(mx, sv[i]);
  }
  mx = blockMax(mx, sb);
  float se = 0.f, sx = 0.f, sxx = 0.f;
  #pragma unroll
  for (int i = 0; i < 4; ++i) {
    float e = expf(sv[i] - mx);
    se += e; sx += e * xv[i]; sxx += e * xv[i] * xv[i];
  }
  se = blockSum(se, sb);
  sx = blockSum(sx, sb);
  sxx = blockSum(sxx, sb);
  if (tid == 0) {
    float mu = sx / se;
    float sg = sqrtf(fmaxf(sxx / se - mu * mu, 1e-12f));
    int j0 = c, j1 = C_ + c;
    pooledn[b * 160 + j0] = (mu - m2[j0]) * rsqrtf(v2[j0] + 1e-5f) * g2[j0] + b2[j0];
    pooledn[b * 160 + j1] = (sg - m2[j1]) * rsqrtf(v2[j1] + 1e-5f) * g2[j1] + b2[j1];
  }
}

// ---- final fc: [4,160] @ [160,192] + b -> out -------------------------------
__global__ __launch_bounds__(256) void fc_k(const float* __restrict__ pooledn, fp fw, fp fb,
                                            float* __restrict__ out) {
  int idx = blockIdx.x * 256 + threadIdx.x;
  if (idx >= 4 * 192) return;
  int b = idx / 192, e = idx % 192;
  float acc = fb[e];
  for (int i = 0; i < 160; ++i) acc += pooledn[b * 160 + i] * fw[i * 192 + e];
  out[idx] = acc;
}

extern "C" void kernel_launch(void* const* d_in, const int* in_sizes, int n_in,
                              void* d_out, int out_size, void* d_ws, size_t ws_size,
                              hipStream_t stream) {
  fp feat   = (fp)d_in[0];
  fp ln1_g  = (fp)d_in[1];  fp ln1_b  = (fp)d_in[2];
  fp in_proj= (fp)d_in[3];
  fp conv_w = (fp)d_in[4];  fp conv_b = (fp)d_in[5];
  fp x_proj = (fp)d_in[6];
  fp dt_w   = (fp)d_in[7];  fp dt_b   = (fp)d_in[8];
  fp A_log  = (fp)d_in[9];  fp Dp     = (fp)d_in[10];
  fp out_proj=(fp)d_in[11];
  fp ln2_g  = (fp)d_in[12]; fp ln2_b  = (fp)d_in[13];
  fp ff_w1  = (fp)d_in[14]; fp ff_b1  = (fp)d_in[15];
  fp ff_w2  = (fp)d_in[16]; fp ff_b2  = (fp)d_in[17];
  fp att_w1 = (fp)d_in[18]; fp att_b1 = (fp)d_in[19];
  fp bn1_g  = (fp)d_in[20]; fp bn1_b  = (fp)d_in[21];
  fp bn1_m  = (fp)d_in[22]; fp bn1_v  = (fp)d_in[23];
  fp att_w2 = (fp)d_in[24]; fp att_b2 = (fp)d_in[25];
  fp bn2_g  = (fp)d_in[26]; fp bn2_b  = (fp)d_in[27];
  fp bn2_m  = (fp)d_in[28]; fp bn2_v  = (fp)d_in[29];
  fp fc_w   = (fp)d_in[30]; fp fc_b   = (fp)d_in[31];

  float* ws   = (float*)d_ws;
  float* x    = ws;               // 256000
  float* xn   = ws + 256000;      // 256000
  float* xz   = ws + 512000;      // 1024000
  float* xcf  = ws + 1536000;     // 512000
  float* xcb  = ws + 2048000;     // 512000
  float* dbc2 = ws + 2560000;     // 236800
  float* dt2  = ws + 2796800;     // 1024000
  float* dtx2 = ws + 3820800;     // 1024000
  float* ygf  = ws + 4844800;     // 512000
  float* ygb  = ws + 5356800;     // 512000
  float* sbuf = ws + 5868800;     // 256000
  float* mbuf = ws + 6124800;     // 256000
  float* meanv= ws + 6380800;     // 320
  float* stdv = ws + 6381120;     // 320
  float* pack = ws + 6381440;     // 768
  float* pooledn = ws + 6382208;  // 640   (end: 6382848 floats = 24.4 MiB)
  float* g1   = xz;               // alias: free after scan
  float* a1b  = dt2;              // alias: pooling only
  float* sc   = dtx2;             // alias: pooling only

  cmn_k<<<320, 256, 0, stream>>>(feat, x);

  for (int l = 0; l < 12; ++l) {
    ln_k<<<800, 256, 0, stream>>>(x, ln1_g + l * 80, ln1_b + l * 80, xn);
    gemm_k<0><<<dim3(5, 50), 256, 0, stream>>>(xn, nullptr, in_proj + l * 25600,
                                               nullptr, nullptr, xz, 320, 80);
    conv_k<<<4000, 256, 0, stream>>>(xz, conv_w + l * 640, conv_b + l * 160, xcf, xcb);
    xdt_k<<<6400, 128, 0, stream>>>(xcf, xcb, x_proj + l * 5920, dt_w + l * 800,
                                    dt_b + l * 160, dbc2, dt2, dtx2);
    scan_k<<<80, 256, 0, stream>>>(dt2, dtx2, dbc2, xcf, xcb, xz,
                                   A_log + l * 2560, Dp + l * 160, ygf, ygb);
    gemm_k<0><<<dim3(2, 50), 256, 0, stream>>>(ygf, ygb, out_proj + l * 12800,
                                               nullptr, nullptr, sbuf, 80, 160);
    ln_k<<<800, 256, 0, stream>>>(sbuf, ln2_g + l * 80, ln2_b + l * 80, mbuf);
    gemm_k<1><<<dim3(5, 50), 256, 0, stream>>>(mbuf, nullptr, ff_w1 + l * 25600,
                                               ff_b1 + l * 320, nullptr, g1, 320, 80);
    gemm_k<2><<<dim3(2, 50), 256, 0, stream>>>(g1, nullptr, ff_w2 + l * 25600,
                                               ff_b2 + l * 80, x, x, 80, 320);
  }

  stats_k<<<320, 256, 0, stream>>>(x, meanv, stdv);
  prep_k<<<3, 256, 0, stream>>>(meanv, stdv, att_w1, att_b1, bn1_g, bn1_b, bn1_m, bn1_v, pack);
  gemm_k<3><<<dim3(2, 50), 256, 0, stream>>>(x, nullptr, att_w1, nullptr, pack, a1b, 128, 80);
  gemm_k<4><<<dim3(2, 50), 256, 0, stream>>>(a1b, nullptr, att_w2, att_b2, nullptr, sc, 80, 128);
  pool_k<<<320, 256, 0, stream>>>(x, sc, bn2_g, bn2_b, bn2_m, bn2_v, pooledn);
  fc_k<<<3, 256, 0, stream>>>(pooledn, fc_w, fc_b, (float*)d_out);
}

// Round 3
// 2375.882 us; speedup vs baseline: 3.4892x; 3.4892x over previous
//
#include <hip/hip_runtime.h>
#include <hip/hip_bf16.h>

#define B_ 4
#define C_ 80
#define T_ 800
#define R_ 3200   // B_*T_
#define DIN 160
#define NST 16
#define NC 16     // time chunks for parallel scan
#define LCH 50    // T_/NC

typedef const float* fp;

__device__ __forceinline__ float blockSum(float v, float* sb) {
  for (int o = 32; o; o >>= 1) v += __shfl_xor(v, o);
  __syncthreads();
  if ((threadIdx.x & 63) == 0) sb[threadIdx.x >> 6] = v;
  __syncthreads();
  return sb[0] + sb[1] + sb[2] + sb[3];
}
__device__ __forceinline__ float blockMax(float v, float* sb) {
  for (int o = 32; o; o >>= 1) v = fmaxf(v, __shfl_xor(v, o));
  __syncthreads();
  if ((threadIdx.x & 63) == 0) sb[threadIdx.x >> 6] = v;
  __syncthreads();
  return fmaxf(fmaxf(sb[0], sb[1]), fmaxf(sb[2], sb[3]));
}

// ---- CMN + transpose: feat [B,C,T] -> x [B*T, C] ----------------------------
__global__ __launch_bounds__(256) void cmn_k(fp feat, float* __restrict__ x) {
  int bc = blockIdx.x;           // 0..319
  int b = bc / C_, c = bc % C_;
  const float* f = feat + (b * C_ + c) * T_;
  __shared__ float sb[4];
  int tid = threadIdx.x;
  float v[4]; float s = 0.f;
  #pragma unroll
  for (int i = 0; i < 4; ++i) {
    int t = tid + i * 256;
    v[i] = (t < T_) ? f[t] : 0.f;
    s += v[i];
  }
  s = blockSum(s, sb);
  float mu = s * (1.f / T_);
  #pragma unroll
  for (int i = 0; i < 4; ++i) {
    int t = tid + i * 256;
    if (t < T_) x[(b * T_ + t) * C_ + c] = v[i] - mu;
  }
}

// ---- LayerNorm over C=80, one wave per row ----------------------------------
__global__ __launch_bounds__(256) void ln_k(const float* __restrict__ in, fp g, fp be,
                                            float* __restrict__ out) {
  int w = threadIdx.x >> 6, lane = threadIdx.x & 63;
  int row = blockIdx.x * 4 + w;
  const float* xr = in + row * C_;
  float v0 = xr[lane];
  float v1 = (lane < 16) ? xr[64 + lane] : 0.f;
  float s = v0 + v1;
  for (int o = 32; o; o >>= 1) s += __shfl_xor(s, o);
  float mu = s * (1.f / C_);
  float d0 = v0 - mu;
  float d1 = (lane < 16) ? (v1 - mu) : 0.f;
  float q = d0 * d0 + d1 * d1;
  for (int o = 32; o; o >>= 1) q += __shfl_xor(q, o);
  float rs = rsqrtf(q * (1.f / C_) + 1e-5f);
  out[row * C_ + lane] = d0 * rs * g[lane] + be[lane];
  if (lane < 16)
    out[row * C_ + 64 + lane] = d1 * rs * g[64 + lane] + be[64 + lane];
}

// ---- generic fp32 GEMM: out[M=3200,N] = (A (+A2)) @ W + epilogue ------------
// EPI: 0=plain 1=bias+gelu 2=bias+residual(extra) 3=att1(pack in extra) 4=bias
template<int EPI>
__global__ __launch_bounds__(256) void gemm_k(const float* __restrict__ A,
    const float* __restrict__ A2, fp W, fp bias,
    const float* __restrict__ extra, float* __restrict__ out, int N, int K) {
  __shared__ float As[64][81];
  __shared__ float Ws[80][64];
  int tid = threadIdx.x;
  int c0 = blockIdx.x * 64;
  int row0 = blockIdx.y * 64;
  int ty = tid >> 4, tx = tid & 15;
  float acc[4][4] = {};
  for (int k0 = 0; k0 < K; k0 += 80) {
    for (int e = tid; e < 64 * 80; e += 256) {
      int r = e / 80, k = e % 80;
      int gk = k0 + k;
      float v = 0.f;
      if (gk < K) {
        v = A[(row0 + r) * K + gk];
        if (A2) v += A2[(row0 + r) * K + gk];
      }
      As[r][k] = v;
    }
    for (int e = tid; e < 80 * 64; e += 256) {
      int k = e >> 6, c = e & 63;
      int gk = k0 + k, gc = c0 + c;
      Ws[k][c] = (gk < K && gc < N) ? W[gk * N + gc] : 0.f;
    }
    __syncthreads();
    #pragma unroll 4
    for (int k = 0; k < 80; ++k) {
      float a0 = As[ty * 4 + 0][k], a1 = As[ty * 4 + 1][k];
      float a2 = As[ty * 4 + 2][k], a3 = As[ty * 4 + 3][k];
      float w0 = Ws[k][tx * 4 + 0], w1 = Ws[k][tx * 4 + 1];
      float w2 = Ws[k][tx * 4 + 2], w3 = Ws[k][tx * 4 + 3];
      acc[0][0] += a0 * w0; acc[0][1] += a0 * w1; acc[0][2] += a0 * w2; acc[0][3] += a0 * w3;
      acc[1][0] += a1 * w0; acc[1][1] += a1 * w1; acc[1][2] += a1 * w2; acc[1][3] += a1 * w3;
      acc[2][0] += a2 * w0; acc[2][1] += a2 * w1; acc[2][2] += a2 * w2; acc[2][3] += a2 * w3;
      acc[3][0] += a3 * w0; acc[3][1] += a3 * w1; acc[3][2] += a3 * w2; acc[3][3] += a3 * w3;
    }
    __syncthreads();
  }
  #pragma unroll
  for (int i = 0; i < 4; ++i) {
    int row = row0 + ty * 4 + i;
    #pragma unroll
    for (int j = 0; j < 4; ++j) {
      int c = c0 + tx * 4 + j;
      if (c < N) {
        float v = acc[i][j];
        if (EPI == 1) { v += bias[c]; v = 0.5f * v * (1.f + erff(v * 0.70710678118f)); }
        else if (EPI == 2) { v += bias[c] + extra[row * N + c]; }
        else if (EPI == 3) {
          v += extra[(row / T_) * 128 + c];
          v = fmaxf(v, 0.f);
          v = v * extra[512 + c] + extra[640 + c];
          v = tanhf(v);
        }
        else if (EPI == 4) { v += bias[c]; }
        out[row * N + c] = v;
      }
    }
  }
}

// ---- causal depthwise conv (K=4) + SiLU, both directions --------------------
__global__ __launch_bounds__(256) void conv_k(const float* __restrict__ xz, fp cw, fp cb,
                                              float* __restrict__ xcf, float* __restrict__ xcb) {
  int idx = blockIdx.x * 256 + threadIdx.x;
  if (idx >= 2 * R_ * DIN) return;
  int dir = idx / (R_ * DIN);
  int rem = idx % (R_ * DIN);
  int r = rem / DIN, d = rem % DIN;
  int b = r / T_, t = r % T_;
  float acc = cb[d];
  #pragma unroll
  for (int k = 0; k < 4; ++k) {
    int tt = t - 3 + k;
    if (tt >= 0) {
      int src = dir ? (T_ - 1 - tt) : tt;
      acc += cw[k * DIN + d] * xz[(b * T_ + src) * 320 + d];
    }
  }
  float sg = 1.f / (1.f + expf(-acc));
  (dir ? xcb : xcf)[r * DIN + d] = acc * sg;
}

// ---- fused x_proj + dt_proj + softplus, per row -----------------------------
__global__ __launch_bounds__(128) void xdt_k(const float* __restrict__ xcf,
    const float* __restrict__ xcb, fp xp, fp dtw, fp dtb,
    float* __restrict__ dbc2, float* __restrict__ dt2) {
  int row = blockIdx.x;               // 0..6399 = dir*R_ + r
  int dir = row / R_, r = row % R_;
  const float* xc = (dir ? xcb : xcf) + r * DIN;
  __shared__ float xl[DIN];
  __shared__ float dl_[5];
  int tid = threadIdx.x;
  for (int e = tid; e < DIN; e += 128) xl[e] = xc[e];
  __syncthreads();
  if (tid < 37) {
    float acc = 0.f;
    for (int i = 0; i < DIN; ++i) acc += xl[i] * xp[i * 37 + tid];
    dbc2[row * 37 + tid] = acc;
    if (tid < 5) dl_[tid] = acc;
  }
  __syncthreads();
  for (int j = tid; j < DIN; j += 128) {
    float v = dtb[j];
    #pragma unroll
    for (int i = 0; i < 5; ++i) v += dl_[i] * dtw[i * DIN + j];
    v = fmaxf(v, 0.f) + log1pf(expf(-fabsf(v)));    // stable softplus
    dt2[row * DIN + j] = v;
  }
}

// ---- chunked parallel scan, phase A: per-chunk (prod, h_end) with h0=0 ------
// block id = (((dir*4+b)*10+dblk)*NC + c); summaries at [bi*256 + dl*16+n]
__global__ __launch_bounds__(256) void scanA_k(const float* __restrict__ dt2,
    const float* __restrict__ xcf, const float* __restrict__ xcb,
    const float* __restrict__ dbc2, fp A_log,
    float* __restrict__ hend, float* __restrict__ pprod) {
  int bi = blockIdx.x;
  int c = bi % NC; int rem = bi / NC;
  int dblk = rem % 10; rem /= 10;
  int b = rem % 4; int dir = rem / 4;
  int d0 = dblk * 16;
  int tid = threadIdx.x, dl = tid >> 4, n = tid & 15;
  int d = d0 + dl;
  float Areg = -__expf(A_log[d * NST + n] * 1.44269504089f);
  // note: A = -exp(A_log); __expf computes 2^x so scale by log2(e)
  __shared__ float sdt[LCH][16], sdx[LCH][16], sB[LCH][16];
  const float* xc = dir ? xcb : xcf;
  int rbase = dir * R_ + b * T_ + c * LCH;
  int rloc0 = b * T_ + c * LCH;
  for (int e = tid; e < LCH * 16; e += 256) {
    int i = e >> 4, j = e & 15;
    int grow = rbase + i;
    float dtv = dt2[grow * DIN + d0 + j];
    sdt[i][j] = dtv;
    sdx[i][j] = dtv * xc[(rloc0 + i) * DIN + d0 + j];
    sB[i][j]  = dbc2[grow * 37 + 5 + j];
  }
  __syncthreads();
  float h = 0.f, P = 1.f;
  #pragma unroll 2
  for (int i = 0; i < LCH; ++i) {
    float a = __expf(sdt[i][dl] * Areg);
    h = a * h + sdx[i][dl] * sB[i][n];
    P *= a;
  }
  hend[bi * 256 + tid] = h;
  pprod[bi * 256 + tid] = P;
}

// ---- phase B: serial combine over NC chunk summaries ------------------------
__global__ __launch_bounds__(256) void scanB_k(const float* __restrict__ hend,
    const float* __restrict__ pprod, float* __restrict__ hstart) {
  int gid = blockIdx.x * 256 + threadIdx.x;   // 80 blocks -> 20480 lanes
  int grp = gid >> 8, lan = gid & 255;
  int base = grp * NC * 256 + lan;
  float h = 0.f;
  #pragma unroll
  for (int cc = 0; cc < NC; ++cc) {
    hstart[base + cc * 256] = h;
    h = pprod[base + cc * 256] * h + hend[base + cc * 256];
  }
}

// ---- phase C: recompute chunk from h_start, gated write ---------------------
__global__ __launch_bounds__(256) void scanC_k(const float* __restrict__ dt2,
    const float* __restrict__ dbc2, const float* __restrict__ xcf,
    const float* __restrict__ xcb, const float* __restrict__ xz,
    fp A_log, fp Dp, const float* __restrict__ hstart,
    float* __restrict__ ygf, float* __restrict__ ygb) {
  int bi = blockIdx.x;
  int c = bi % NC; int rem = bi / NC;
  int dblk = rem % 10; rem /= 10;
  int b = rem % 4; int dir = rem / 4;
  int d0 = dblk * 16;
  int tid = threadIdx.x, dl = tid >> 4, n = tid & 15;
  int d = d0 + dl;
  float Areg = -__expf(A_log[d * NST + n] * 1.44269504089f);
  __shared__ float sdt[LCH][16], sdx[LCH][16], sB[LCH][16], sC[LCH][16];
  __shared__ float sY[LCH][16];
  const float* xc = dir ? xcb : xcf;
  float* yg = dir ? ygb : ygf;
  int rbase = dir * R_ + b * T_ + c * LCH;
  int rloc0 = b * T_ + c * LCH;
  for (int e = tid; e < LCH * 16; e += 256) {
    int i = e >> 4, j = e & 15;
    int grow = rbase + i;
    float dtv = dt2[grow * DIN + d0 + j];
    sdt[i][j] = dtv;
    sdx[i][j] = dtv * xc[(rloc0 + i) * DIN + d0 + j];
    sB[i][j]  = dbc2[grow * 37 + 5 + j];
    sC[i][j]  = dbc2[grow * 37 + 21 + j];
  }
  float h = hstart[bi * 256 + tid];
  __syncthreads();
  for (int i = 0; i < LCH; ++i) {
    float a = __expf(sdt[i][dl] * Areg);
    h = a * h + sdx[i][dl] * sB[i][n];
    float y = h * sC[i][n];
    y += __shfl_xor(y, 1);
    y += __shfl_xor(y, 2);
    y += __shfl_xor(y, 4);
    y += __shfl_xor(y, 8);
    if (n == 0) sY[i][dl] = y;
  }
  __syncthreads();
  for (int e = tid; e < LCH * 16; e += 256) {
    int i = e >> 4, j = e & 15;
    int t = c * LCH + i;
    int rloc = b * T_ + t;
    float xcv = xc[rloc * DIN + d0 + j];
    int orow = dir ? (b * T_ + (T_ - 1 - t)) : rloc;
    float z = xz[orow * 320 + 160 + d0 + j];
    float sg = 1.f / (1.f + __expf(-z * 1.44269504089f));
    yg[orow * DIN + d0 + j] = (sY[i][j] + xcv * Dp[d0 + j]) * (z * sg);
  }
}

// ---- pooling: per-(b,c) mean/std over T -------------------------------------
__global__ __launch_bounds__(256) void stats_k(const float* __restrict__ x,
                                               float* __restrict__ meanv, float* __restrict__ stdv) {
  int bc = blockIdx.x; int b = bc / C_, c = bc % C_;
  __shared__ float sb[4];
  int tid = threadIdx.x;
  float v[4]; float s = 0.f;
  #pragma unroll
  for (int i = 0; i < 4; ++i) {
    int t = tid + i * 256;
    v[i] = (t < T_) ? x[(b * T_ + t) * C_ + c] : 0.f;
    s += v[i];
  }
  s = blockSum(s, sb);
  float mu = s * (1.f / T_);
  float q = 0.f;
  #pragma unroll
  for (int i = 0; i < 4; ++i) {
    int t = tid + i * 256;
    if (t < T_) { float dd = v[i] - mu; q += dd * dd; }
  }
  q = blockSum(q, sb);
  if (tid == 0) { meanv[bc] = mu; stdv[bc] = sqrtf(fmaxf(q * (1.f / T_), 1e-12f)); }
}

// ---- att1 pack: bias2[b][d] (mean/std branches + b1), bn1 affine ------------
__global__ __launch_bounds__(256) void prep_k(const float* __restrict__ meanv,
    const float* __restrict__ stdv, fp w1, fp ab1, fp g1p, fp b1p, fp m1p, fp v1p,
    float* __restrict__ pack) {
  int idx = blockIdx.x * 256 + threadIdx.x;
  if (idx < 512) {
    int b = idx / 128, dcol = idx % 128;
    float acc = ab1[dcol];
    for (int c = 0; c < C_; ++c) {
      acc += meanv[b * C_ + c] * w1[(C_ + c) * 128 + dcol];
      acc += stdv[b * C_ + c] * w1[(2 * C_ + c) * 128 + dcol];
    }
    pack[idx] = acc;
  } else if (idx < 640) {
    int dcol = idx - 512;
    float kv = g1p[dcol] * rsqrtf(v1p[dcol] + 1e-5f);
    pack[512 + dcol] = kv;
    pack[640 + dcol] = b1p[dcol] - m1p[dcol] * kv;
  }
}

// ---- softmax over T + weighted stats + bn2 ----------------------------------
__global__ __launch_bounds__(256) void pool_k(const float* __restrict__ x,
    const float* __restrict__ scores, fp g2, fp b2, fp m2, fp v2,
    float* __restrict__ pooledn) {
  int bc = blockIdx.x; int b = bc / C_, c = bc % C_;
  __shared__ float sb[4];
  int tid = threadIdx.x;
  float sv[4], xv[4];
  float mx = -1e30f;
  #pragma unroll
  for (int i = 0; i < 4; ++i) {
    int t = tid + i * 256;
    if (t < T_) { sv[i] = scores[(b * T_ + t) * C_ + c]; xv[i] = x[(b * T_ + t) * C_ + c]; }
    else { sv[i] = -1e30f; xv[i] = 0.f; }
    mx = fmaxf(mx, sv[i]);
  }
  mx = blockMax(mx, sb);
  float se = 0.f, sx = 0.f, sxx = 0.f;
  #pragma unroll
  for (int i = 0; i < 4; ++i) {
    float e = expf(sv[i] - mx);
    se += e; sx += e * xv[i]; sxx += e * xv[i] * xv[i];
  }
  se = blockSum(se, sb);
  sx = blockSum(sx, sb);
  sxx = blockSum(sxx, sb);
  if (tid == 0) {
    float mu = sx / se;
    float sg = sqrtf(fmaxf(sxx / se - mu * mu, 1e-12f));
    int j0 = c, j1 = C_ + c;
    pooledn[b * 160 + j0] = (mu - m2[j0]) * rsqrtf(v2[j0] + 1e-5f) * g2[j0] + b2[j0];
    pooledn[b * 160 + j1] = (sg - m2[j1]) * rsqrtf(v2[j1] + 1e-5f) * g2[j1] + b2[j1];
  }
}

// ---- final fc: [4,160] @ [160,192] + b -> out -------------------------------
__global__ __launch_bounds__(256) void fc_k(const float* __restrict__ pooledn, fp fw, fp fb,
                                            float* __restrict__ out) {
  int idx = blockIdx.x * 256 + threadIdx.x;
  if (idx >= 4 * 192) return;
  int b = idx / 192, e = idx % 192;
  float acc = fb[e];
  for (int i = 0; i < 160; ++i) acc += pooledn[b * 160 + i] * fw[i * 192 + e];
  out[idx] = acc;
}

extern "C" void kernel_launch(void* const* d_in, const int* in_sizes, int n_in,
                              void* d_out, int out_size, void* d_ws, size_t ws_size,
                              hipStream_t stream) {
  fp feat   = (fp)d_in[0];
  fp ln1_g  = (fp)d_in[1];  fp ln1_b  = (fp)d_in[2];
  fp in_proj= (fp)d_in[3];
  fp conv_w = (fp)d_in[4];  fp conv_b = (fp)d_in[5];
  fp x_proj = (fp)d_in[6];
  fp dt_w   = (fp)d_in[7];  fp dt_b   = (fp)d_in[8];
  fp A_log  = (fp)d_in[9];  fp Dp     = (fp)d_in[10];
  fp out_proj=(fp)d_in[11];
  fp ln2_g  = (fp)d_in[12]; fp ln2_b  = (fp)d_in[13];
  fp ff_w1  = (fp)d_in[14]; fp ff_b1  = (fp)d_in[15];
  fp ff_w2  = (fp)d_in[16]; fp ff_b2  = (fp)d_in[17];
  fp att_w1 = (fp)d_in[18]; fp att_b1 = (fp)d_in[19];
  fp bn1_g  = (fp)d_in[20]; fp bn1_b  = (fp)d_in[21];
  fp bn1_m  = (fp)d_in[22]; fp bn1_v  = (fp)d_in[23];
  fp att_w2 = (fp)d_in[24]; fp att_b2 = (fp)d_in[25];
  fp bn2_g  = (fp)d_in[26]; fp bn2_b  = (fp)d_in[27];
  fp bn2_m  = (fp)d_in[28]; fp bn2_v  = (fp)d_in[29];
  fp fc_w   = (fp)d_in[30]; fp fc_b   = (fp)d_in[31];

  float* ws   = (float*)d_ws;
  float* x    = ws;               // 256000
  float* xn   = ws + 256000;      // 256000
  float* xz   = ws + 512000;      // 1024000
  float* xcf  = ws + 1536000;     // 512000
  float* xcb  = ws + 2048000;     // 512000
  float* dbc2 = ws + 2560000;     // 236800
  float* dt2  = ws + 2796800;     // 1024000
  float* hend = ws + 3820800;     // 327680  (old dtx2 slot, 1024000 total)
  float* pprod= ws + 4148480;     // 327680
  float* hstart=ws + 4476160;     // 327680  (ends 4803840 < 4844800)
  float* ygf  = ws + 4844800;     // 512000
  float* ygb  = ws + 5356800;     // 512000
  float* sbuf = ws + 5868800;     // 256000
  float* mbuf = ws + 6124800;     // 256000
  float* meanv= ws + 6380800;     // 320
  float* stdv = ws + 6381120;     // 320
  float* pack = ws + 6381440;     // 768
  float* pooledn = ws + 6382208;  // 640   (end: 6382848 floats = 24.4 MiB)
  float* g1   = xz;               // alias: free after scan
  float* a1b  = dt2;              // alias: pooling only
  float* sc   = ws + 3820800;     // alias old dtx2 slot: pooling only

  cmn_k<<<320, 256, 0, stream>>>(feat, x);

  for (int l = 0; l < 12; ++l) {
    ln_k<<<800, 256, 0, stream>>>(x, ln1_g + l * 80, ln1_b + l * 80, xn);
    gemm_k<0><<<dim3(5, 50), 256, 0, stream>>>(xn, nullptr, in_proj + l * 25600,
                                               nullptr, nullptr, xz, 320, 80);
    conv_k<<<4000, 256, 0, stream>>>(xz, conv_w + l * 640, conv_b + l * 160, xcf, xcb);
    xdt_k<<<6400, 128, 0, stream>>>(xcf, xcb, x_proj + l * 5920, dt_w + l * 800,
                                    dt_b + l * 160, dbc2, dt2);
    scanA_k<<<1280, 256, 0, stream>>>(dt2, xcf, xcb, dbc2, A_log + l * 2560, hend, pprod);
    scanB_k<<<80, 256, 0, stream>>>(hend, pprod, hstart);
    scanC_k<<<1280, 256, 0, stream>>>(dt2, dbc2, xcf, xcb, xz, A_log + l * 2560,
                                      Dp + l * 160, hstart, ygf, ygb);
    gemm_k<0><<<dim3(2, 50), 256, 0, stream>>>(ygf, ygb, out_proj + l * 12800,
                                               nullptr, nullptr, sbuf, 80, 160);
    ln_k<<<800, 256, 0, stream>>>(sbuf, ln2_g + l * 80, ln2_b + l * 80, mbuf);
    gemm_k<1><<<dim3(5, 50), 256, 0, stream>>>(mbuf, nullptr, ff_w1 + l * 25600,
                                               ff_b1 + l * 320, nullptr, g1, 320, 80);
    gemm_k<2><<<dim3(2, 50), 256, 0, stream>>>(g1, nullptr, ff_w2 + l * 25600,
                                               ff_b2 + l * 80, x, x, 80, 320);
  }

  stats_k<<<320, 256, 0, stream>>>(x, meanv, stdv);
  prep_k<<<3, 256, 0, stream>>>(meanv, stdv, att_w1, att_b1, bn1_g, bn1_b, bn1_m, bn1_v, pack);
  gemm_k<3><<<dim3(2, 50), 256, 0, stream>>>(x, nullptr, att_w1, nullptr, pack, a1b, 128, 80);
  gemm_k<4><<<dim3(2, 50), 256, 0, stream>>>(a1b, nullptr, att_w2, att_b2, nullptr, sc, 80, 128);
  pool_k<<<320, 256, 0, stream>>>(x, sc, bn2_g, bn2_b, bn2_m, bn2_v, pooledn);
  fc_k<<<3, 256, 0, stream>>>(pooledn, fc_w, fc_b, (float*)d_out);
}

// Round 4
// 1939.043 us; speedup vs baseline: 4.2752x; 1.2253x over previous
//
#include <hip/hip_runtime.h>
#include <hip/hip_bf16.h>

#define B_ 4
#define C_ 80
#define T_ 800
#define R_ 3200   // B_*T_
#define DIN 160
#define NST 16
#define NC 16     // time chunks for parallel scan
#define LCH 50    // T_/NC

typedef const float* fp;

__device__ __forceinline__ float blockSum(float v, float* sb) {
  for (int o = 32; o; o >>= 1) v += __shfl_xor(v, o);
  __syncthreads();
  if ((threadIdx.x & 63) == 0) sb[threadIdx.x >> 6] = v;
  __syncthreads();
  return sb[0] + sb[1] + sb[2] + sb[3];
}
__device__ __forceinline__ float blockMax(float v, float* sb) {
  for (int o = 32; o; o >>= 1) v = fmaxf(v, __shfl_xor(v, o));
  __syncthreads();
  if ((threadIdx.x & 63) == 0) sb[threadIdx.x >> 6] = v;
  __syncthreads();
  return fmaxf(fmaxf(sb[0], sb[1]), fmaxf(sb[2], sb[3]));
}

// ---- CMN + transpose: feat [B,C,T] -> x [B*T, C] ----------------------------
__global__ __launch_bounds__(256) void cmn_k(fp feat, float* __restrict__ x) {
  int bc = blockIdx.x;           // 0..319
  int b = bc / C_, c = bc % C_;
  const float* f = feat + (b * C_ + c) * T_;
  __shared__ float sb[4];
  int tid = threadIdx.x;
  float v[4]; float s = 0.f;
  #pragma unroll
  for (int i = 0; i < 4; ++i) {
    int t = tid + i * 256;
    v[i] = (t < T_) ? f[t] : 0.f;
    s += v[i];
  }
  s = blockSum(s, sb);
  float mu = s * (1.f / T_);
  #pragma unroll
  for (int i = 0; i < 4; ++i) {
    int t = tid + i * 256;
    if (t < T_) x[(b * T_ + t) * C_ + c] = v[i] - mu;
  }
}

// ---- LayerNorm over C=80, one wave per row ----------------------------------
__global__ __launch_bounds__(256) void ln_k(const float* __restrict__ in, fp g, fp be,
                                            float* __restrict__ out) {
  int w = threadIdx.x >> 6, lane = threadIdx.x & 63;
  int row = blockIdx.x * 4 + w;
  const float* xr = in + row * C_;
  float v0 = xr[lane];
  float v1 = (lane < 16) ? xr[64 + lane] : 0.f;
  float s = v0 + v1;
  for (int o = 32; o; o >>= 1) s += __shfl_xor(s, o);
  float mu = s * (1.f / C_);
  float d0 = v0 - mu;
  float d1 = (lane < 16) ? (v1 - mu) : 0.f;
  float q = d0 * d0 + d1 * d1;
  for (int o = 32; o; o >>= 1) q += __shfl_xor(q, o);
  float rs = rsqrtf(q * (1.f / C_) + 1e-5f);
  out[row * C_ + lane] = d0 * rs * g[lane] + be[lane];
  if (lane < 16)
    out[row * C_ + 64 + lane] = d1 * rs * g[64 + lane] + be[64 + lane];
}

// ---- fp32 GEMM, 16-row x TN-col tiles, 1D grid with XCD swizzle -------------
// out[M=3200,N] = (A (+A2)) @ W + epilogue
// EPI: 0=plain 1=bias+gelu 2=bias+residual(extra) 3=att1(pack in extra) 4=bias
// grid = (N/TN) * 200 blocks (must be % 8 == 0), block = 256
template<int EPI, int TN>
__global__ __launch_bounds__(256) void gemm_k(const float* __restrict__ A,
    const float* __restrict__ A2, fp W, fp bias,
    const float* __restrict__ extra, float* __restrict__ out, int N, int K) {
  constexpr int TNT = TN / 16;       // cols per thread (4 or 5)
  __shared__ float As[16][81];
  __shared__ float Ws[80][TN];
  int ncol = N / TN;
  int nwg = gridDim.x;
  int bid = blockIdx.x;
  int q = nwg >> 3;
  int swz = (bid & 7) * q + (bid >> 3);   // bijective: nwg % 8 == 0
  int cx = swz % ncol, ry = swz / ncol;
  int c0 = cx * TN, row0 = ry * 16;
  int tid = threadIdx.x;
  int ty = tid >> 4, tx = tid & 15;
  float acc[TNT] = {};
  for (int k0 = 0; k0 < K; k0 += 80) {
    for (int e = tid; e < 16 * 80; e += 256) {
      int r = e / 80, k = e % 80;
      int gk = k0 + k;
      float v = 0.f;
      if (gk < K) {
        v = A[(row0 + r) * K + gk];
        if (A2) v += A2[(row0 + r) * K + gk];
      }
      As[r][k] = v;
    }
    for (int e = tid; e < 80 * TN; e += 256) {
      int k = e / TN, c = e % TN;
      int gk = k0 + k;
      Ws[k][c] = (gk < K) ? W[gk * N + c0 + c] : 0.f;
    }
    __syncthreads();
    #pragma unroll 4
    for (int k = 0; k < 80; ++k) {
      float a = As[ty][k];
      #pragma unroll
      for (int j = 0; j < TNT; ++j)
        acc[j] += a * Ws[k][tx * TNT + j];
    }
    __syncthreads();
  }
  int row = row0 + ty;
  #pragma unroll
  for (int j = 0; j < TNT; ++j) {
    int c = c0 + tx * TNT + j;
    float v = acc[j];
    if (EPI == 1) { v += bias[c]; v = 0.5f * v * (1.f + erff(v * 0.70710678118f)); }
    else if (EPI == 2) { v += bias[c] + extra[row * N + c]; }
    else if (EPI == 3) {
      v += extra[(row / T_) * 128 + c];
      v = fmaxf(v, 0.f);
      v = v * extra[512 + c] + extra[640 + c];
      v = tanhf(v);
    }
    else if (EPI == 4) { v += bias[c]; }
    out[row * N + c] = v;
  }
}

// ---- causal depthwise conv (K=4) + SiLU, both directions --------------------
__global__ __launch_bounds__(256) void conv_k(const float* __restrict__ xz, fp cw, fp cb,
                                              float* __restrict__ xcf, float* __restrict__ xcb) {
  int idx = blockIdx.x * 256 + threadIdx.x;
  if (idx >= 2 * R_ * DIN) return;
  int dir = idx / (R_ * DIN);
  int rem = idx % (R_ * DIN);
  int r = rem / DIN, d = rem % DIN;
  int b = r / T_, t = r % T_;
  float acc = cb[d];
  #pragma unroll
  for (int k = 0; k < 4; ++k) {
    int tt = t - 3 + k;
    if (tt >= 0) {
      int src = dir ? (T_ - 1 - tt) : tt;
      acc += cw[k * DIN + d] * xz[(b * T_ + src) * 320 + d];
    }
  }
  float sg = 1.f / (1.f + expf(-acc));
  (dir ? xcb : xcf)[r * DIN + d] = acc * sg;
}

// ---- fused x_proj + dt_proj + softplus, per row -----------------------------
__global__ __launch_bounds__(128) void xdt_k(const float* __restrict__ xcf,
    const float* __restrict__ xcb, fp xp, fp dtw, fp dtb,
    float* __restrict__ dbc2, float* __restrict__ dt2) {
  int row = blockIdx.x;               // 0..6399 = dir*R_ + r
  int dir = row / R_, r = row % R_;
  const float* xc = (dir ? xcb : xcf) + r * DIN;
  __shared__ float xl[DIN];
  __shared__ float dl_[5];
  int tid = threadIdx.x;
  for (int e = tid; e < DIN; e += 128) xl[e] = xc[e];
  __syncthreads();
  if (tid < 37) {
    float acc = 0.f;
    for (int i = 0; i < DIN; ++i) acc += xl[i] * xp[i * 37 + tid];
    dbc2[row * 37 + tid] = acc;
    if (tid < 5) dl_[tid] = acc;
  }
  __syncthreads();
  for (int j = tid; j < DIN; j += 128) {
    float v = dtb[j];
    #pragma unroll
    for (int i = 0; i < 5; ++i) v += dl_[i] * dtw[i * DIN + j];
    v = fmaxf(v, 0.f) + log1pf(expf(-fabsf(v)));    // stable softplus
    dt2[row * DIN + j] = v;
  }
}

// ---- chunked parallel scan, phase A: per-chunk (prod, h_end) with h0=0 ------
__global__ __launch_bounds__(256) void scanA_k(const float* __restrict__ dt2,
    const float* __restrict__ xcf, const float* __restrict__ xcb,
    const float* __restrict__ dbc2, fp A_log,
    float* __restrict__ hend, float* __restrict__ pprod) {
  int bi = blockIdx.x;
  int c = bi % NC; int rem = bi / NC;
  int dblk = rem % 10; rem /= 10;
  int b = rem % 4; int dir = rem / 4;
  int d0 = dblk * 16;
  int tid = threadIdx.x, dl = tid >> 4, n = tid & 15;
  int d = d0 + dl;
  float Areg = -__expf(A_log[d * NST + n] * 1.44269504089f);
  __shared__ float sdt[LCH][16], sdx[LCH][16], sB[LCH][16];
  const float* xc = dir ? xcb : xcf;
  int rbase = dir * R_ + b * T_ + c * LCH;
  int rloc0 = b * T_ + c * LCH;
  for (int e = tid; e < LCH * 16; e += 256) {
    int i = e >> 4, j = e & 15;
    int grow = rbase + i;
    float dtv = dt2[grow * DIN + d0 + j];
    sdt[i][j] = dtv;
    sdx[i][j] = dtv * xc[(rloc0 + i) * DIN + d0 + j];
    sB[i][j]  = dbc2[grow * 37 + 5 + j];
  }
  __syncthreads();
  float h = 0.f, P = 1.f;
  #pragma unroll 2
  for (int i = 0; i < LCH; ++i) {
    float a = __expf(sdt[i][dl] * Areg);
    h = a * h + sdx[i][dl] * sB[i][n];
    P *= a;
  }
  hend[bi * 256 + tid] = h;
  pprod[bi * 256 + tid] = P;
}

// ---- phase B: serial combine over NC chunk summaries ------------------------
__global__ __launch_bounds__(256) void scanB_k(const float* __restrict__ hend,
    const float* __restrict__ pprod, float* __restrict__ hstart) {
  int gid = blockIdx.x * 256 + threadIdx.x;   // 80 blocks -> 20480 lanes
  int grp = gid >> 8, lan = gid & 255;
  int base = grp * NC * 256 + lan;
  float h = 0.f;
  #pragma unroll
  for (int cc = 0; cc < NC; ++cc) {
    hstart[base + cc * 256] = h;
    h = pprod[base + cc * 256] * h + hend[base + cc * 256];
  }
}

// ---- phase C: recompute chunk from h_start, gated write ---------------------
__global__ __launch_bounds__(256) void scanC_k(const float* __restrict__ dt2,
    const float* __restrict__ dbc2, const float* __restrict__ xcf,
    const float* __restrict__ xcb, const float* __restrict__ xz,
    fp A_log, fp Dp, const float* __restrict__ hstart,
    float* __restrict__ ygf, float* __restrict__ ygb) {
  int bi = blockIdx.x;
  int c = bi % NC; int rem = bi / NC;
  int dblk = rem % 10; rem /= 10;
  int b = rem % 4; int dir = rem / 4;
  int d0 = dblk * 16;
  int tid = threadIdx.x, dl = tid >> 4, n = tid & 15;
  int d = d0 + dl;
  float Areg = -__expf(A_log[d * NST + n] * 1.44269504089f);
  __shared__ float sdt[LCH][16], sdx[LCH][16], sB[LCH][16], sC[LCH][16];
  __shared__ float sY[LCH][16];
  const float* xc = dir ? xcb : xcf;
  float* yg = dir ? ygb : ygf;
  int rbase = dir * R_ + b * T_ + c * LCH;
  int rloc0 = b * T_ + c * LCH;
  for (int e = tid; e < LCH * 16; e += 256) {
    int i = e >> 4, j = e & 15;
    int grow = rbase + i;
    float dtv = dt2[grow * DIN + d0 + j];
    sdt[i][j] = dtv;
    sdx[i][j] = dtv * xc[(rloc0 + i) * DIN + d0 + j];
    sB[i][j]  = dbc2[grow * 37 + 5 + j];
    sC[i][j]  = dbc2[grow * 37 + 21 + j];
  }
  float h = hstart[bi * 256 + tid];
  __syncthreads();
  for (int i = 0; i < LCH; ++i) {
    float a = __expf(sdt[i][dl] * Areg);
    h = a * h + sdx[i][dl] * sB[i][n];
    float y = h * sC[i][n];
    y += __shfl_xor(y, 1);
    y += __shfl_xor(y, 2);
    y += __shfl_xor(y, 4);
    y += __shfl_xor(y, 8);
    if (n == 0) sY[i][dl] = y;
  }
  __syncthreads();
  for (int e = tid; e < LCH * 16; e += 256) {
    int i = e >> 4, j = e & 15;
    int t = c * LCH + i;
    int rloc = b * T_ + t;
    float xcv = xc[rloc * DIN + d0 + j];
    int orow = dir ? (b * T_ + (T_ - 1 - t)) : rloc;
    float z = xz[orow * 320 + 160 + d0 + j];
    float sg = 1.f / (1.f + __expf(-z * 1.44269504089f));
    yg[orow * DIN + d0 + j] = (sY[i][j] + xcv * Dp[d0 + j]) * (z * sg);
  }
}

// ---- pooling: per-(b,c) mean/std over T -------------------------------------
__global__ __launch_bounds__(256) void stats_k(const float* __restrict__ x,
                                               float* __restrict__ meanv, float* __restrict__ stdv) {
  int bc = blockIdx.x; int b = bc / C_, c = bc % C_;
  __shared__ float sb[4];
  int tid = threadIdx.x;
  float v[4]; float s = 0.f;
  #pragma unroll
  for (int i = 0; i < 4; ++i) {
    int t = tid + i * 256;
    v[i] = (t < T_) ? x[(b * T_ + t) * C_ + c] : 0.f;
    s += v[i];
  }
  s = blockSum(s, sb);
  float mu = s * (1.f / T_);
  float q = 0.f;
  #pragma unroll
  for (int i = 0; i < 4; ++i) {
    int t = tid + i * 256;
    if (t < T_) { float dd = v[i] - mu; q += dd * dd; }
  }
  q = blockSum(q, sb);
  if (tid == 0) { meanv[bc] = mu; stdv[bc] = sqrtf(fmaxf(q * (1.f / T_), 1e-12f)); }
}

// ---- att1 pack: bias2[b][d] (mean/std branches + b1), bn1 affine ------------
__global__ __launch_bounds__(256) void prep_k(const float* __restrict__ meanv,
    const float* __restrict__ stdv, fp w1, fp ab1, fp g1p, fp b1p, fp m1p, fp v1p,
    float* __restrict__ pack) {
  int idx = blockIdx.x * 256 + threadIdx.x;
  if (idx < 512) {
    int b = idx / 128, dcol = idx % 128;
    float acc = ab1[dcol];
    for (int c = 0; c < C_; ++c) {
      acc += meanv[b * C_ + c] * w1[(C_ + c) * 128 + dcol];
      acc += stdv[b * C_ + c] * w1[(2 * C_ + c) * 128 + dcol];
    }
    pack[idx] = acc;
  } else if (idx < 640) {
    int dcol = idx - 512;
    float kv = g1p[dcol] * rsqrtf(v1p[dcol] + 1e-5f);
    pack[512 + dcol] = kv;
    pack[640 + dcol] = b1p[dcol] - m1p[dcol] * kv;
  }
}

// ---- softmax over T + weighted stats + bn2 ----------------------------------
__global__ __launch_bounds__(256) void pool_k(const float* __restrict__ x,
    const float* __restrict__ scores, fp g2, fp b2, fp m2, fp v2,
    float* __restrict__ pooledn) {
  int bc = blockIdx.x; int b = bc / C_, c = bc % C_;
  __shared__ float sb[4];
  int tid = threadIdx.x;
  float sv[4], xv[4];
  float mx = -1e30f;
  #pragma unroll
  for (int i = 0; i < 4; ++i) {
    int t = tid + i * 256;
    if (t < T_) { sv[i] = scores[(b * T_ + t) * C_ + c]; xv[i] = x[(b * T_ + t) * C_ + c]; }
    else { sv[i] = -1e30f; xv[i] = 0.f; }
    mx = fmaxf(mx, sv[i]);
  }
  mx = blockMax(mx, sb);
  float se = 0.f, sx = 0.f, sxx = 0.f;
  #pragma unroll
  for (int i = 0; i < 4; ++i) {
    float e = expf(sv[i] - mx);
    se += e; sx += e * xv[i]; sxx += e * xv[i] * xv[i];
  }
  se = blockSum(se, sb);
  sx = blockSum(sx, sb);
  sxx = blockSum(sxx, sb);
  if (tid == 0) {
    float mu = sx / se;
    float sg = sqrtf(fmaxf(sxx / se - mu * mu, 1e-12f));
    int j0 = c, j1 = C_ + c;
    pooledn[b * 160 + j0] = (mu - m2[j0]) * rsqrtf(v2[j0] + 1e-5f) * g2[j0] + b2[j0];
    pooledn[b * 160 + j1] = (sg - m2[j1]) * rsqrtf(v2[j1] + 1e-5f) * g2[j1] + b2[j1];
  }
}

// ---- final fc: [4,160] @ [160,192] + b -> out -------------------------------
__global__ __launch_bounds__(256) void fc_k(const float* __restrict__ pooledn, fp fw, fp fb,
                                            float* __restrict__ out) {
  int idx = blockIdx.x * 256 + threadIdx.x;
  if (idx >= 4 * 192) return;
  int b = idx / 192, e = idx % 192;
  float acc = fb[e];
  for (int i = 0; i < 160; ++i) acc += pooledn[b * 160 + i] * fw[i * 192 + e];
  out[idx] = acc;
}

extern "C" void kernel_launch(void* const* d_in, const int* in_sizes, int n_in,
                              void* d_out, int out_size, void* d_ws, size_t ws_size,
                              hipStream_t stream) {
  fp feat   = (fp)d_in[0];
  fp ln1_g  = (fp)d_in[1];  fp ln1_b  = (fp)d_in[2];
  fp in_proj= (fp)d_in[3];
  fp conv_w = (fp)d_in[4];  fp conv_b = (fp)d_in[5];
  fp x_proj = (fp)d_in[6];
  fp dt_w   = (fp)d_in[7];  fp dt_b   = (fp)d_in[8];
  fp A_log  = (fp)d_in[9];  fp Dp     = (fp)d_in[10];
  fp out_proj=(fp)d_in[11];
  fp ln2_g  = (fp)d_in[12]; fp ln2_b  = (fp)d_in[13];
  fp ff_w1  = (fp)d_in[14]; fp ff_b1  = (fp)d_in[15];
  fp ff_w2  = (fp)d_in[16]; fp ff_b2  = (fp)d_in[17];
  fp att_w1 = (fp)d_in[18]; fp att_b1 = (fp)d_in[19];
  fp bn1_g  = (fp)d_in[20]; fp bn1_b  = (fp)d_in[21];
  fp bn1_m  = (fp)d_in[22]; fp bn1_v  = (fp)d_in[23];
  fp att_w2 = (fp)d_in[24]; fp att_b2 = (fp)d_in[25];
  fp bn2_g  = (fp)d_in[26]; fp bn2_b  = (fp)d_in[27];
  fp bn2_m  = (fp)d_in[28]; fp bn2_v  = (fp)d_in[29];
  fp fc_w   = (fp)d_in[30]; fp fc_b   = (fp)d_in[31];

  float* ws   = (float*)d_ws;
  float* x    = ws;               // 256000
  float* xn   = ws + 256000;      // 256000
  float* xz   = ws + 512000;      // 1024000
  float* xcf  = ws + 1536000;     // 512000
  float* xcb  = ws + 2048000;     // 512000
  float* dbc2 = ws + 2560000;     // 236800
  float* dt2  = ws + 2796800;     // 1024000
  float* hend = ws + 3820800;     // 327680
  float* pprod= ws + 4148480;     // 327680
  float* hstart=ws + 4476160;     // 327680
  float* ygf  = ws + 4844800;     // 512000
  float* ygb  = ws + 5356800;     // 512000
  float* sbuf = ws + 5868800;     // 256000
  float* mbuf = ws + 6124800;     // 256000
  float* meanv= ws + 6380800;     // 320
  float* stdv = ws + 6381120;     // 320
  float* pack = ws + 6381440;     // 768
  float* pooledn = ws + 6382208;  // 640
  float* g1   = xz;               // alias: free after scan
  float* a1b  = dt2;              // alias: pooling only
  float* sc   = ws + 3820800;     // alias old scan slot: pooling only

  cmn_k<<<320, 256, 0, stream>>>(feat, x);

  for (int l = 0; l < 12; ++l) {
    ln_k<<<800, 256, 0, stream>>>(x, ln1_g + l * 80, ln1_b + l * 80, xn);
    gemm_k<0, 64><<<1000, 256, 0, stream>>>(xn, nullptr, in_proj + l * 25600,
                                            nullptr, nullptr, xz, 320, 80);
    conv_k<<<4000, 256, 0, stream>>>(xz, conv_w + l * 640, conv_b + l * 160, xcf, xcb);
    xdt_k<<<6400, 128, 0, stream>>>(xcf, xcb, x_proj + l * 5920, dt_w + l * 800,
                                    dt_b + l * 160, dbc2, dt2);
    scanA_k<<<1280, 256, 0, stream>>>(dt2, xcf, xcb, dbc2, A_log + l * 2560, hend, pprod);
    scanB_k<<<80, 256, 0, stream>>>(hend, pprod, hstart);
    scanC_k<<<1280, 256, 0, stream>>>(dt2, dbc2, xcf, xcb, xz, A_log + l * 2560,
                                      Dp + l * 160, hstart, ygf, ygb);
    gemm_k<0, 80><<<200, 256, 0, stream>>>(ygf, ygb, out_proj + l * 12800,
                                           nullptr, nullptr, sbuf, 80, 160);
    ln_k<<<800, 256, 0, stream>>>(sbuf, ln2_g + l * 80, ln2_b + l * 80, mbuf);
    gemm_k<1, 64><<<1000, 256, 0, stream>>>(mbuf, nullptr, ff_w1 + l * 25600,
                                            ff_b1 + l * 320, nullptr, g1, 320, 80);
    gemm_k<2, 80><<<200, 256, 0, stream>>>(g1, nullptr, ff_w2 + l * 25600,
                                           ff_b2 + l * 80, x, x, 80, 320);
  }

  stats_k<<<320, 256, 0, stream>>>(x, meanv, stdv);
  prep_k<<<3, 256, 0, stream>>>(meanv, stdv, att_w1, att_b1, bn1_g, bn1_b, bn1_m, bn1_v, pack);
  gemm_k<3, 64><<<400, 256, 0, stream>>>(x, nullptr, att_w1, nullptr, pack, a1b, 128, 80);
  gemm_k<4, 80><<<200, 256, 0, stream>>>(a1b, nullptr, att_w2, att_b2, nullptr, sc, 80, 128);
  pool_k<<<320, 256, 0, stream>>>(x, sc, bn2_g, bn2_b, bn2_m, bn2_v, pooledn);
  fc_k<<<3, 256, 0, stream>>>(pooledn, fc_w, fc_b, (float*)d_out);
}

// Round 5
// 1312.511 us; speedup vs baseline: 6.3160x; 1.4774x over previous
//
#include <hip/hip_runtime.h>
#include <hip/hip_bf16.h>

#define B_ 4
#define C_ 80
#define T_ 800
#define R_ 3200   // B_*T_
#define DIN 160
#define NST 16
#define NC 16     // time chunks for parallel scan
#define LCH 50    // T_/NC

typedef const float* fp;

__device__ __forceinline__ void g2l16(const float* g, float* l) {
  __builtin_amdgcn_global_load_lds(
      (const __attribute__((address_space(1))) void*)g,
      (__attribute__((address_space(3))) void*)l,
      16, 0, 0);
}

__device__ __forceinline__ float blockSum(float v, float* sb) {
  for (int o = 32; o; o >>= 1) v += __shfl_xor(v, o);
  __syncthreads();
  if ((threadIdx.x & 63) == 0) sb[threadIdx.x >> 6] = v;
  __syncthreads();
  return sb[0] + sb[1] + sb[2] + sb[3];
}
__device__ __forceinline__ float blockMax(float v, float* sb) {
  for (int o = 32; o; o >>= 1) v = fmaxf(v, __shfl_xor(v, o));
  __syncthreads();
  if ((threadIdx.x & 63) == 0) sb[threadIdx.x >> 6] = v;
  __syncthreads();
  return fmaxf(fmaxf(sb[0], sb[1]), fmaxf(sb[2], sb[3]));
}

// ---- CMN + transpose: feat [B,C,T] -> x [B*T, C] ----------------------------
__global__ __launch_bounds__(256) void cmn_k(fp feat, float* __restrict__ x) {
  int bc = blockIdx.x;           // 0..319
  int b = bc / C_, c = bc % C_;
  const float* f = feat + (b * C_ + c) * T_;
  __shared__ float sb[4];
  int tid = threadIdx.x;
  float v[4]; float s = 0.f;
  #pragma unroll
  for (int i = 0; i < 4; ++i) {
    int t = tid + i * 256;
    v[i] = (t < T_) ? f[t] : 0.f;
    s += v[i];
  }
  s = blockSum(s, sb);
  float mu = s * (1.f / T_);
  #pragma unroll
  for (int i = 0; i < 4; ++i) {
    int t = tid + i * 256;
    if (t < T_) x[(b * T_ + t) * C_ + c] = v[i] - mu;
  }
}

// ---- LayerNorm over C=80, one wave per row ----------------------------------
__global__ __launch_bounds__(256) void ln_k(const float* __restrict__ in, fp g, fp be,
                                            float* __restrict__ out) {
  int w = threadIdx.x >> 6, lane = threadIdx.x & 63;
  int row = blockIdx.x * 4 + w;
  const float* xr = in + row * C_;
  float v0 = xr[lane];
  float v1 = (lane < 16) ? xr[64 + lane] : 0.f;
  float s = v0 + v1;
  for (int o = 32; o; o >>= 1) s += __shfl_xor(s, o);
  float mu = s * (1.f / C_);
  float d0 = v0 - mu;
  float d1 = (lane < 16) ? (v1 - mu) : 0.f;
  float q = d0 * d0 + d1 * d1;
  for (int o = 32; o; o >>= 1) q += __shfl_xor(q, o);
  float rs = rsqrtf(q * (1.f / C_) + 1e-5f);
  out[row * C_ + lane] = d0 * rs * g[lane] + be[lane];
  if (lane < 16)
    out[row * C_ + 64 + lane] = d1 * rs * g[64 + lane] + be[64 + lane];
}

// ---- fp32 GEMM, 16-row x TN-col tiles, async global_load_lds staging --------
// out[M=3200,N] = A @ W + epilogue. All tile shapes exact (no guards).
// EPI: 0=plain 1=bias+gelu 2=bias+residual(extra) 3=att1(pack in extra) 4=bias
// WSTACK: W rows indexed mod 160 (out_proj applied to [ygf|ygb])
template<int EPI, int TN, int BK, int WSTACK>
__global__ __launch_bounds__(256) void gemm_k(const float* __restrict__ A,
    fp W, fp bias, const float* __restrict__ extra,
    float* __restrict__ out, int N, int K) {
  constexpr int TNT = TN / 16;
  constexpr int A_EL = 16 * BK;
  constexpr int W_EL = BK * TN;
  constexpr int A_CH = A_EL / 256;
  constexpr int W_CH = W_EL / 256;
  constexpr int TOT_CH = A_CH + W_CH;
  __shared__ float SL[A_EL + W_EL];
  float* As = SL;            // [16][BK] unpadded
  float* Ws = SL + A_EL;     // [BK][TN]
  int ncol = N / TN;
  int nwg = gridDim.x;
  int bid = blockIdx.x;
  int q = nwg >> 3;
  int swz = (bid & 7) * q + (bid >> 3);   // bijective: nwg % 8 == 0
  int cx = swz % ncol, ry = swz / ncol;
  int c0 = cx * TN, row0 = ry * 16;
  int tid = threadIdx.x;
  int wv = tid >> 6, ln = tid & 63;
  int ty = tid >> 4, tx = tid & 15;
  float acc[TNT] = {};
  for (int k0 = 0; k0 < K; k0 += BK) {
    if (k0) __syncthreads();
    for (int ch = wv; ch < TOT_CH; ch += 4) {
      int m = ch * 256 + ln * 4;
      const float* g;
      if (ch < A_CH) {
        int r = m / BK, kk = m - r * BK;
        g = A + (row0 + r) * K + k0 + kk;
      } else {
        int mm = m - A_EL;
        int kr = mm / TN, cc = mm - kr * TN;
        int gk = k0 + kr;
        if (WSTACK) gk = (gk >= 160) ? gk - 160 : gk;
        g = W + gk * N + c0 + cc;
      }
      int lo = __builtin_amdgcn_readfirstlane(ch * 256);
      g2l16(g, SL + lo);
    }
    __syncthreads();
    #pragma unroll 4
    for (int k = 0; k < BK; ++k) {
      float a = As[ty * BK + k];
      #pragma unroll
      for (int j = 0; j < TNT; ++j)
        acc[j] += a * Ws[k * TN + tx * TNT + j];
    }
  }
  int row = row0 + ty;
  #pragma unroll
  for (int j = 0; j < TNT; ++j) {
    int c = c0 + tx * TNT + j;
    float v = acc[j];
    if (EPI == 1) { v += bias[c]; v = 0.5f * v * (1.f + erff(v * 0.70710678118f)); }
    else if (EPI == 2) { v += bias[c] + extra[row * N + c]; }
    else if (EPI == 3) {
      v += extra[(row / T_) * 128 + c];
      v = fmaxf(v, 0.f);
      v = v * extra[512 + c] + extra[640 + c];
      v = tanhf(v);
    }
    else if (EPI == 4) { v += bias[c]; }
    out[row * N + c] = v;
  }
}

// ---- causal depthwise conv (K=4) + SiLU, both directions --------------------
__global__ __launch_bounds__(256) void conv_k(const float* __restrict__ xz, fp cw, fp cb,
                                              float* __restrict__ xcf, float* __restrict__ xcb) {
  int idx = blockIdx.x * 256 + threadIdx.x;
  if (idx >= 2 * R_ * DIN) return;
  int dir = idx / (R_ * DIN);
  int rem = idx % (R_ * DIN);
  int r = rem / DIN, d = rem % DIN;
  int b = r / T_, t = r % T_;
  float acc = cb[d];
  #pragma unroll
  for (int k = 0; k < 4; ++k) {
    int tt = t - 3 + k;
    if (tt >= 0) {
      int src = dir ? (T_ - 1 - tt) : tt;
      acc += cw[k * DIN + d] * xz[(b * T_ + src) * 320 + d];
    }
  }
  float sg = 1.f / (1.f + expf(-acc));
  (dir ? xcb : xcf)[r * DIN + d] = acc * sg;
}

// ---- fused x_proj + dt_proj + softplus, per row -----------------------------
__global__ __launch_bounds__(128) void xdt_k(const float* __restrict__ xcf,
    const float* __restrict__ xcb, fp xp, fp dtw, fp dtb,
    float* __restrict__ dbc2, float* __restrict__ dt2) {
  int row = blockIdx.x;               // 0..6399 = dir*R_ + r
  int dir = row / R_, r = row % R_;
  const float* xc = (dir ? xcb : xcf) + r * DIN;
  __shared__ float xl[DIN];
  __shared__ float dl_[5];
  int tid = threadIdx.x;
  for (int e = tid; e < DIN; e += 128) xl[e] = xc[e];
  __syncthreads();
  if (tid < 37) {
    float acc = 0.f;
    for (int i = 0; i < DIN; ++i) acc += xl[i] * xp[i * 37 + tid];
    dbc2[row * 37 + tid] = acc;
    if (tid < 5) dl_[tid] = acc;
  }
  __syncthreads();
  for (int j = tid; j < DIN; j += 128) {
    float v = dtb[j];
    #pragma unroll
    for (int i = 0; i < 5; ++i) v += dl_[i] * dtw[i * DIN + j];
    v = fmaxf(v, 0.f) + log1pf(expf(-fabsf(v)));    // stable softplus
    dt2[row * DIN + j] = v;
  }
}

// ---- chunked parallel scan, phase A: per-chunk (prod, h_end) with h0=0 ------
__global__ __launch_bounds__(256) void scanA_k(const float* __restrict__ dt2,
    const float* __restrict__ xcf, const float* __restrict__ xcb,
    const float* __restrict__ dbc2, fp A_log,
    float* __restrict__ hend, float* __restrict__ pprod) {
  int bi = blockIdx.x;
  int c = bi % NC; int rem = bi / NC;
  int dblk = rem % 10; rem /= 10;
  int b = rem % 4; int dir = rem / 4;
  int d0 = dblk * 16;
  int tid = threadIdx.x, dl = tid >> 4, n = tid & 15;
  int d = d0 + dl;
  float Areg = -__expf(A_log[d * NST + n] * 1.44269504089f);
  __shared__ float sdt[LCH][16], sdx[LCH][16], sB[LCH][16];
  const float* xc = dir ? xcb : xcf;
  int rbase = dir * R_ + b * T_ + c * LCH;
  int rloc0 = b * T_ + c * LCH;
  for (int e = tid; e < LCH * 16; e += 256) {
    int i = e >> 4, j = e & 15;
    int grow = rbase + i;
    float dtv = dt2[grow * DIN + d0 + j];
    sdt[i][j] = dtv;
    sdx[i][j] = dtv * xc[(rloc0 + i) * DIN + d0 + j];
    sB[i][j]  = dbc2[grow * 37 + 5 + j];
  }
  __syncthreads();
  float h = 0.f, P = 1.f;
  #pragma unroll 2
  for (int i = 0; i < LCH; ++i) {
    float a = __expf(sdt[i][dl] * Areg);
    h = a * h + sdx[i][dl] * sB[i][n];
    P *= a;
  }
  hend[bi * 256 + tid] = h;
  pprod[bi * 256 + tid] = P;
}

// ---- phase B: serial combine over NC chunk summaries ------------------------
__global__ __launch_bounds__(256) void scanB_k(const float* __restrict__ hend,
    const float* __restrict__ pprod, float* __restrict__ hstart) {
  int gid = blockIdx.x * 256 + threadIdx.x;   // 80 blocks -> 20480 lanes
  int grp = gid >> 8, lan = gid & 255;
  int base = grp * NC * 256 + lan;
  float h = 0.f;
  #pragma unroll
  for (int cc = 0; cc < NC; ++cc) {
    hstart[base + cc * 256] = h;
    h = pprod[base + cc * 256] * h + hend[base + cc * 256];
  }
}

// ---- phase C: recompute chunk from h_start, gated write to ygcat ------------
// ygcat [3200][320]: cols 0-159 fwd, 160-319 bwd (both un-flipped)
__global__ __launch_bounds__(256) void scanC_k(const float* __restrict__ dt2,
    const float* __restrict__ dbc2, const float* __restrict__ xcf,
    const float* __restrict__ xcb, const float* __restrict__ xz,
    fp A_log, fp Dp, const float* __restrict__ hstart,
    float* __restrict__ ygcat) {
  int bi = blockIdx.x;
  int c = bi % NC; int rem = bi / NC;
  int dblk = rem % 10; rem /= 10;
  int b = rem % 4; int dir = rem / 4;
  int d0 = dblk * 16;
  int tid = threadIdx.x, dl = tid >> 4, n = tid & 15;
  int d = d0 + dl;
  float Areg = -__expf(A_log[d * NST + n] * 1.44269504089f);
  __shared__ float sdt[LCH][16], sdx[LCH][16], sB[LCH][16], sC[LCH][16];
  __shared__ float sY[LCH][16];
  const float* xc = dir ? xcb : xcf;
  int rbase = dir * R_ + b * T_ + c * LCH;
  int rloc0 = b * T_ + c * LCH;
  for (int e = tid; e < LCH * 16; e += 256) {
    int i = e >> 4, j = e & 15;
    int grow = rbase + i;
    float dtv = dt2[grow * DIN + d0 + j];
    sdt[i][j] = dtv;
    sdx[i][j] = dtv * xc[(rloc0 + i) * DIN + d0 + j];
    sB[i][j]  = dbc2[grow * 37 + 5 + j];
    sC[i][j]  = dbc2[grow * 37 + 21 + j];
  }
  float h = hstart[bi * 256 + tid];
  __syncthreads();
  for (int i = 0; i < LCH; ++i) {
    float a = __expf(sdt[i][dl] * Areg);
    h = a * h + sdx[i][dl] * sB[i][n];
    float y = h * sC[i][n];
    y += __shfl_xor(y, 1);
    y += __shfl_xor(y, 2);
    y += __shfl_xor(y, 4);
    y += __shfl_xor(y, 8);
    if (n == 0) sY[i][dl] = y;
  }
  __syncthreads();
  for (int e = tid; e < LCH * 16; e += 256) {
    int i = e >> 4, j = e & 15;
    int t = c * LCH + i;
    int rloc = b * T_ + t;
    float xcv = xc[rloc * DIN + d0 + j];
    int orow = dir ? (b * T_ + (T_ - 1 - t)) : rloc;
    float z = xz[orow * 320 + 160 + d0 + j];
    float sg = 1.f / (1.f + __expf(-z * 1.44269504089f));
    ygcat[orow * 320 + dir * 160 + d0 + j] = (sY[i][j] + xcv * Dp[d0 + j]) * (z * sg);
  }
}

// ---- pooling: per-(b,c) mean/std over T -------------------------------------
__global__ __launch_bounds__(256) void stats_k(const float* __restrict__ x,
                                               float* __restrict__ meanv, float* __restrict__ stdv) {
  int bc = blockIdx.x; int b = bc / C_, c = bc % C_;
  __shared__ float sb[4];
  int tid = threadIdx.x;
  float v[4]; float s = 0.f;
  #pragma unroll
  for (int i = 0; i < 4; ++i) {
    int t = tid + i * 256;
    v[i] = (t < T_) ? x[(b * T_ + t) * C_ + c] : 0.f;
    s += v[i];
  }
  s = blockSum(s, sb);
  float mu = s * (1.f / T_);
  float q = 0.f;
  #pragma unroll
  for (int i = 0; i < 4; ++i) {
    int t = tid + i * 256;
    if (t < T_) { float dd = v[i] - mu; q += dd * dd; }
  }
  q = blockSum(q, sb);
  if (tid == 0) { meanv[bc] = mu; stdv[bc] = sqrtf(fmaxf(q * (1.f / T_), 1e-12f)); }
}

// ---- att1 pack: bias2[b][d] (mean/std branches + b1), bn1 affine ------------
__global__ __launch_bounds__(256) void prep_k(const float* __restrict__ meanv,
    const float* __restrict__ stdv, fp w1, fp ab1, fp g1p, fp b1p, fp m1p, fp v1p,
    float* __restrict__ pack) {
  int idx = blockIdx.x * 256 + threadIdx.x;
  if (idx < 512) {
    int b = idx / 128, dcol = idx % 128;
    float acc = ab1[dcol];
    for (int c = 0; c < C_; ++c) {
      acc += meanv[b * C_ + c] * w1[(C_ + c) * 128 + dcol];
      acc += stdv[b * C_ + c] * w1[(2 * C_ + c) * 128 + dcol];
    }
    pack[idx] = acc;
  } else if (idx < 640) {
    int dcol = idx - 512;
    float kv = g1p[dcol] * rsqrtf(v1p[dcol] + 1e-5f);
    pack[512 + dcol] = kv;
    pack[640 + dcol] = b1p[dcol] - m1p[dcol] * kv;
  }
}

// ---- softmax over T + weighted stats + bn2 ----------------------------------
__global__ __launch_bounds__(256) void pool_k(const float* __restrict__ x,
    const float* __restrict__ scores, fp g2, fp b2, fp m2, fp v2,
    float* __restrict__ pooledn) {
  int bc = blockIdx.x; int b = bc / C_, c = bc % C_;
  __shared__ float sb[4];
  int tid = threadIdx.x;
  float sv[4], xv[4];
  float mx = -1e30f;
  #pragma unroll
  for (int i = 0; i < 4; ++i) {
    int t = tid + i * 256;
    if (t < T_) { sv[i] = scores[(b * T_ + t) * C_ + c]; xv[i] = x[(b * T_ + t) * C_ + c]; }
    else { sv[i] = -1e30f; xv[i] = 0.f; }
    mx = fmaxf(mx, sv[i]);
  }
  mx = blockMax(mx, sb);
  float se = 0.f, sx = 0.f, sxx = 0.f;
  #pragma unroll
  for (int i = 0; i < 4; ++i) {
    float e = expf(sv[i] - mx);
    se += e; sx += e * xv[i]; sxx += e * xv[i] * xv[i];
  }
  se = blockSum(se, sb);
  sx = blockSum(sx, sb);
  sxx = blockSum(sxx, sb);
  if (tid == 0) {
    float mu = sx / se;
    float sg = sqrtf(fmaxf(sxx / se - mu * mu, 1e-12f));
    int j0 = c, j1 = C_ + c;
    pooledn[b * 160 + j0] = (mu - m2[j0]) * rsqrtf(v2[j0] + 1e-5f) * g2[j0] + b2[j0];
    pooledn[b * 160 + j1] = (sg - m2[j1]) * rsqrtf(v2[j1] + 1e-5f) * g2[j1] + b2[j1];
  }
}

// ---- final fc: [4,160] @ [160,192] + b -> out -------------------------------
__global__ __launch_bounds__(256) void fc_k(const float* __restrict__ pooledn, fp fw, fp fb,
                                            float* __restrict__ out) {
  int idx = blockIdx.x * 256 + threadIdx.x;
  if (idx >= 4 * 192) return;
  int b = idx / 192, e = idx % 192;
  float acc = fb[e];
  for (int i = 0; i < 160; ++i) acc += pooledn[b * 160 + i] * fw[i * 192 + e];
  out[idx] = acc;
}

extern "C" void kernel_launch(void* const* d_in, const int* in_sizes, int n_in,
                              void* d_out, int out_size, void* d_ws, size_t ws_size,
                              hipStream_t stream) {
  fp feat   = (fp)d_in[0];
  fp ln1_g  = (fp)d_in[1];  fp ln1_b  = (fp)d_in[2];
  fp in_proj= (fp)d_in[3];
  fp conv_w = (fp)d_in[4];  fp conv_b = (fp)d_in[5];
  fp x_proj = (fp)d_in[6];
  fp dt_w   = (fp)d_in[7];  fp dt_b   = (fp)d_in[8];
  fp A_log  = (fp)d_in[9];  fp Dp     = (fp)d_in[10];
  fp out_proj=(fp)d_in[11];
  fp ln2_g  = (fp)d_in[12]; fp ln2_b  = (fp)d_in[13];
  fp ff_w1  = (fp)d_in[14]; fp ff_b1  = (fp)d_in[15];
  fp ff_w2  = (fp)d_in[16]; fp ff_b2  = (fp)d_in[17];
  fp att_w1 = (fp)d_in[18]; fp att_b1 = (fp)d_in[19];
  fp bn1_g  = (fp)d_in[20]; fp bn1_b  = (fp)d_in[21];
  fp bn1_m  = (fp)d_in[22]; fp bn1_v  = (fp)d_in[23];
  fp att_w2 = (fp)d_in[24]; fp att_b2 = (fp)d_in[25];
  fp bn2_g  = (fp)d_in[26]; fp bn2_b  = (fp)d_in[27];
  fp bn2_m  = (fp)d_in[28]; fp bn2_v  = (fp)d_in[29];
  fp fc_w   = (fp)d_in[30]; fp fc_b   = (fp)d_in[31];

  float* ws   = (float*)d_ws;
  float* x    = ws;               // 256000
  float* xn   = ws + 256000;      // 256000
  float* xz   = ws + 512000;      // 1024000
  float* xcf  = ws + 1536000;     // 512000
  float* xcb  = ws + 2048000;     // 512000
  float* dbc2 = ws + 2560000;     // 236800
  float* dt2  = ws + 2796800;     // 1024000
  float* hend = ws + 3820800;     // 327680
  float* pprod= ws + 4148480;     // 327680
  float* hstart=ws + 4476160;     // 327680
  float* ygcat= ws + 4844800;     // 1024000  [3200][320] fwd|bwd
  float* sbuf = ws + 5868800;     // 256000
  float* mbuf = ws + 6124800;     // 256000
  float* meanv= ws + 6380800;     // 320
  float* stdv = ws + 6381120;     // 320
  float* pack = ws + 6381440;     // 768
  float* pooledn = ws + 6382208;  // 640
  float* g1   = xz;               // alias: free after scan
  float* a1b  = dt2;              // alias: pooling only
  float* sc   = ws + 3820800;     // alias old scan slot: pooling only

  cmn_k<<<320, 256, 0, stream>>>(feat, x);

  for (int l = 0; l < 12; ++l) {
    ln_k<<<800, 256, 0, stream>>>(x, ln1_g + l * 80, ln1_b + l * 80, xn);
    gemm_k<0, 64, 80, 0><<<1000, 256, 0, stream>>>(xn, in_proj + l * 25600,
                                                   nullptr, nullptr, xz, 320, 80);
    conv_k<<<4000, 256, 0, stream>>>(xz, conv_w + l * 640, conv_b + l * 160, xcf, xcb);
    xdt_k<<<6400, 128, 0, stream>>>(xcf, xcb, x_proj + l * 5920, dt_w + l * 800,
                                    dt_b + l * 160, dbc2, dt2);
    scanA_k<<<1280, 256, 0, stream>>>(dt2, xcf, xcb, dbc2, A_log + l * 2560, hend, pprod);
    scanB_k<<<80, 256, 0, stream>>>(hend, pprod, hstart);
    scanC_k<<<1280, 256, 0, stream>>>(dt2, dbc2, xcf, xcb, xz, A_log + l * 2560,
                                      Dp + l * 160, hstart, ygcat);
    gemm_k<0, 80, 80, 1><<<200, 256, 0, stream>>>(ygcat, out_proj + l * 12800,
                                                  nullptr, nullptr, sbuf, 80, 320);
    ln_k<<<800, 256, 0, stream>>>(sbuf, ln2_g + l * 80, ln2_b + l * 80, mbuf);
    gemm_k<1, 64, 80, 0><<<1000, 256, 0, stream>>>(mbuf, ff_w1 + l * 25600,
                                                   ff_b1 + l * 320, nullptr, g1, 320, 80);
    gemm_k<2, 80, 80, 0><<<200, 256, 0, stream>>>(g1, ff_w2 + l * 25600,
                                                  ff_b2 + l * 80, x, x, 80, 320);
  }

  stats_k<<<320, 256, 0, stream>>>(x, meanv, stdv);
  prep_k<<<3, 256, 0, stream>>>(meanv, stdv, att_w1, att_b1, bn1_g, bn1_b, bn1_m, bn1_v, pack);
  gemm_k<3, 64, 80, 0><<<400, 256, 0, stream>>>(x, att_w1, nullptr, pack, a1b, 128, 80);
  gemm_k<4, 80, 64, 0><<<200, 256, 0, stream>>>(a1b, att_w2, att_b2, nullptr, sc, 80, 128);
  pool_k<<<320, 256, 0, stream>>>(x, sc, bn2_g, bn2_b, bn2_m, bn2_v, pooledn);
  fc_k<<<3, 256, 0, stream>>>(pooledn, fc_w, fc_b, (float*)d_out);
}